// Round 1
// baseline (167.972 us; speedup 1.0000x reference)
//
#include <hip/hip_runtime.h>
#include <stdint.h>

typedef __attribute__((ext_vector_type(8))) __bf16 bf16x8;
typedef __attribute__((ext_vector_type(16))) float f32x16;
typedef __attribute__((ext_vector_type(4))) unsigned int u32x4;
typedef unsigned int u32;
typedef unsigned short u16;

#define THETA 0.7f

// PHT = Laplacian target + eps (H*(t/H) == t exactly for H=+-1.0 here)
__host__ __device__ constexpr float pht_val(int q) {
  return (q == 12) ? (-4.0f + 1e-6f)
       : (q == 7 || q == 11 || q == 13 || q == 17) ? (1.0f + 1e-6f)
       : 1e-6f;
}

// ---------------- kernel 1: build K_eff, packed as MFMA A-fragments -------
// Rotation gather tables (derived from numpy f32 trig + int() truncation):
//  keff[p] += PHT[q]*w[q] for each (p,q); a=0 identity handled separately.
__global__ __launch_bounds__(256) void k_prep(const float* __restrict__ wgt,
                                              const float* __restrict__ alpha,
                                              u16* __restrict__ apack) {
  int t = blockIdx.x * 256 + threadIdx.x;   // 4096 threads: (o, ci)
  int o = t >> 6, ci = t & 63;
  const float* wp = wgt + ((size_t)(o * 64 + ci)) * 25;
  float wv[25], sumw = 0.f;
#pragma unroll
  for (int p = 0; p < 25; ++p) { wv[p] = wp[p]; sumw += wv[p]; }
  float keff[25];
#pragma unroll
  for (int p = 0; p < 25; ++p) keff[p] = pht_val(p) * wv[p];  // a=0 (identity)
  // a=1 (10), a=2 (5), a=3, a=4, a=5, a=6 (5), a=7 (10):
  constexpr int TP[33] = {0,1,2,3,4,6,7,9,12,13,  0,1,2,3,4,  0, 0, 0,
                          0,5,10,15,20,  0,5,6,10,11,12,15,17,20,21};
  constexpr int TQ[33] = {5,6,12,17,23,10,16,22,20,21,  0,5,10,15,20,  5, 0, 5,
                          0,6,7,8,9,  5,6,2,12,8,4,17,9,23,14};
#pragma unroll
  for (int e = 0; e < 33; ++e) keff[TP[e]] += pht_val(TQ[e]) * wv[TQ[e]];

  float al = alpha[0];
  int kc = ci >> 4, oh = o >> 5;
  int lane = ((ci >> 3) & 1) * 32 + (o & 31);   // A-frag: lane=(k/8)*32+m
#pragma unroll
  for (int p = 0; p < 25; ++p) {
    float v = al * (keff[p] * 0.125f);
    if (p == 12) v -= THETA * sumw;             // fold 1x1 branch into center
    u32 u = __builtin_bit_cast(u32, v);
    u16 b = (u16)((u + 0x7fffu + ((u >> 16) & 1u)) >> 16);  // RNE fp32->bf16
    size_t idx = ((((size_t)p * 4 + kc) * 2 + oh) * 64 + lane) * 8 + (ci & 7);
    apack[idx] = b;
  }
}

// ---------------- kernel 2: x (NCHW fp32) -> X_t[n][y][px][i] bf16 --------
__global__ __launch_bounds__(256) void k_xcast(const float* __restrict__ x,
                                               u16* __restrict__ xt) {
  __shared__ u16 lt[64][130];                 // +2 pad breaks bank conflicts
  int bid = blockIdx.x;                       // n*128 + y
  int n = bid >> 7, y = bid & 127;
  const float* xb = x + (size_t)n * 64 * 16384 + (size_t)y * 128;
  int t = threadIdx.x;
#pragma unroll
  for (int it = 0; it < 32; ++it) {
    int idx = it * 256 + t;
    int i = idx >> 7, px = idx & 127;
    float v = xb[(size_t)i * 16384 + px];     // coalesced along px
    u32 u = __builtin_bit_cast(u32, v);
    lt[i][px] = (u16)((u + 0x7fffu + ((u >> 16) & 1u)) >> 16);
  }
  __syncthreads();
  u16* xtb = xt + (size_t)(n * 128 + y) * 8192;
#pragma unroll
  for (int it = 0; it < 32; ++it) {
    int idx = it * 256 + t;
    int px = idx >> 6, i = idx & 63;
    xtb[(size_t)px * 64 + i] = lt[i][px];     // coalesced along i
  }
}

// ---------------- kernel 3: conv via 32x32x16 bf16 MFMA -------------------
// Block: 512 thr (8 waves), C = 64o x (4 rows x 128 px). LDS: 8 rows of
// [132 cols][64 i] bf16 = 132 KB, XOR-swizzled in 16B granules within each
// 128B (col) block: phys_g = g ^ (col & 7). Staged by global_load_lds with
// pre-swizzled global source (linear LDS dest).
#define ROWB 16896   // 132 cols * 128 B

__global__ __launch_bounds__(512) void k_conv(const u16* __restrict__ xt,
                                              const u32x4* __restrict__ apack,
                                              float* __restrict__ out) {
  __shared__ u32x4 tile4[8 * ROWB / 16];
  char* tile = (char*)tile4;
  int bid = blockIdx.x;
  int lg = (bid & 7) * 128 + (bid >> 3);      // bijective XCD swizzle (nwg%8==0)
  int n = lg >> 5, yt = lg & 31;
  int y0 = yt * 4;
  int tid = threadIdx.x;
  int l = tid & 63, wv = tid >> 6;

  // ---- stage: wave wv stages LDS row wv (src row y0+wv-2) ----
  {
    int r = wv;
    int sy = y0 + r - 2;
    char* rowbase = tile + r * ROWB;
    if ((unsigned)sy < 128u) {
      const char* src = (const char*)(xt + (size_t)(n * 128 + sy) * 8192);
      int lo3 = l >> 3, l7 = l & 7;
      int glog = l7 ^ ((2 + lo3) & 7);        // inverse swizzle on source
      int soff = lo3 * 128 + glog * 16;
#pragma unroll
      for (int it = 0; it < 16; ++it) {       // 16 x 1KB = full 128-px row
        __builtin_amdgcn_global_load_lds(
            (const __attribute__((address_space(1))) u32*)(src + it * 1024 + soff),
            (__attribute__((address_space(3))) u32*)(rowbase + 256 + it * 1024),
            16, 0, 0);
      }
      if (l < 32) {                           // zero halo cols {0,1,130,131}
        int ii = l >> 3;
        int c = ii + ((ii >> 1) * 128);
        u32x4 z = {0u, 0u, 0u, 0u};
        *(u32x4*)(rowbase + c * 128 + (l & 7) * 16) = z;
      }
    } else {                                  // out-of-image row -> zeros
      u32x4 z = {0u, 0u, 0u, 0u};
#pragma unroll
      for (int it = 0; it < 17; ++it) {
        int off = it * 1024 + l * 16;
        if (off < ROWB) *(u32x4*)(rowbase + off) = z;
      }
    }
  }
  __syncthreads();

  // ---- compute: wave = (q = output row 0..3, oh = o-half 0..1) ----
  int q = wv >> 1, oh = wv & 1;
  int l31 = l & 31, lhi = l >> 5;
  f32x16 acc[4] = {};
  const u32x4* apb = apack + (size_t)oh * 64 + l;
  for (int p = 0; p < 25; ++p) {
    int dy = p / 5, dx = p % 5;
    const u32x4* ap = apb + (size_t)p * 512;
    u32x4 a[4];
#pragma unroll
    for (int kc = 0; kc < 4; ++kc) a[kc] = ap[(size_t)kc * 128];  // L2-hot
    const char* pb = tile + (q + dy) * ROWB + (l31 + dx) * 128;
    int c7 = (l31 + dx) & 7;                  // nt*32 doesn't change col&7
#pragma unroll
    for (int kc = 0; kc < 4; ++kc) {
      int gx = (((kc * 2 + lhi) ^ c7) << 4);  // swizzled granule offset
#pragma unroll
      for (int nt = 0; nt < 4; ++nt) {
        u32x4 bv = *(const u32x4*)(pb + nt * 4096 + gx);
        acc[nt] = __builtin_amdgcn_mfma_f32_32x32x16_bf16(
            __builtin_bit_cast(bf16x8, a[kc]),
            __builtin_bit_cast(bf16x8, bv),
            acc[nt], 0, 0, 0);
      }
    }
  }

  // ---- epilogue: C/D 32x32 layout col=lane&31, row=(reg&3)+8*(reg>>2)+4*(lane>>5)
  float* ob = out + ((size_t)n * 64 + oh * 32) * 16384 + (size_t)(y0 + q) * 128;
#pragma unroll
  for (int nt = 0; nt < 4; ++nt) {
#pragma unroll
    for (int rg = 0; rg < 16; ++rg) {
      int rowc = (rg & 3) + 8 * (rg >> 2) + 4 * lhi;
      ob[(size_t)rowc * 16384 + nt * 32 + l31] = acc[nt][rg];
    }
  }
}

extern "C" void kernel_launch(void* const* d_in, const int* in_sizes, int n_in,
                              void* d_out, int out_size, void* d_ws, size_t ws_size,
                              hipStream_t stream) {
  const float* x     = (const float*)d_in[0];   // (32,64,128,128) fp32
  const float* wgt   = (const float*)d_in[1];   // (64,64,5,5) fp32
  const float* alpha = (const float*)d_in[2];   // (1,) fp32
  float* out = (float*)d_out;

  u16* apack = (u16*)d_ws;                                  // 204800 B
  u16* xt    = (u16*)((char*)d_ws + (1 << 20));             // 64 MiB

  k_prep <<<16,   256, 0, stream>>>(wgt, alpha, apack);
  k_xcast<<<4096, 256, 0, stream>>>(x, xt);
  k_conv <<<1024, 512, 0, stream>>>(xt, (const u32x4*)apack, out);
}